// Round 1
// baseline (250.333 us; speedup 1.0000x reference)
//
#include <hip/hip_runtime.h>
#include <math.h>

// Problem constants (SHAPE = (1, 128, 48, 48, 48), FILTERS = (1,3,3,3,1))
#define NCH      128
#define SPATIAL  110592            // 48*48*48
#define BLOCKS_X 27                // SPATIAL / ELEMS_PER_BLOCK
#define ELEMS_PER_BLOCK 4096
#define THREADS  256
#define ITERS    4                 // float4 iterations per thread: 4*256*4 = 4096 elems

#define QT 21.416413017506358f     // log(2/1e-9 - 1)

__device__ __forceinline__ float frcp(float x){ return __builtin_amdgcn_rcpf(x); }
// tanh(x) = 1 - 2/(exp(2x)+1); saturates correctly at +-1 for large |x|
__device__ __forceinline__ float ftanh(float x){ return 1.0f - 2.0f*frcp(__expf(2.0f*x) + 1.0f); }
__device__ __forceinline__ float fsig(float x){ return frcp(1.0f + __expf(-x)); }
// softplus(x) = max(x,0) + log1p(exp(-|x|))  (robust for both signs)
__device__ __forceinline__ float fsoftplus(float x){ return fmaxf(x, 0.0f) + log1pf(__expf(-fabsf(x))); }

struct Params {
    float w0[3], w1[9], w2[9], w3[3];
    float t0[3], t1[3], t2[3];
    float B0[3], B1[3], B2[3], B3;
};

// z: scalar input; per-channel 4-layer CDF MLP (softplus weights pre-applied).
template<bool USE_F>
__device__ __forceinline__ float eval_mlp(float z, const Params& P){
    float h0 = fmaf(P.w0[0], z, P.B0[0]);
    float h1 = fmaf(P.w0[1], z, P.B0[1]);
    float h2 = fmaf(P.w0[2], z, P.B0[2]);
    if (USE_F){
        h0 = fmaf(P.t0[0], ftanh(h0), h0);
        h1 = fmaf(P.t0[1], ftanh(h1), h1);
        h2 = fmaf(P.t0[2], ftanh(h2), h2);
    }
    float g0 = fmaf(P.w1[0],h0, fmaf(P.w1[1],h1, fmaf(P.w1[2],h2, P.B1[0])));
    float g1 = fmaf(P.w1[3],h0, fmaf(P.w1[4],h1, fmaf(P.w1[5],h2, P.B1[1])));
    float g2 = fmaf(P.w1[6],h0, fmaf(P.w1[7],h1, fmaf(P.w1[8],h2, P.B1[2])));
    if (USE_F){
        g0 = fmaf(P.t1[0], ftanh(g0), g0);
        g1 = fmaf(P.t1[1], ftanh(g1), g1);
        g2 = fmaf(P.t1[2], ftanh(g2), g2);
    }
    h0 = fmaf(P.w2[0],g0, fmaf(P.w2[1],g1, fmaf(P.w2[2],g2, P.B2[0])));
    h1 = fmaf(P.w2[3],g0, fmaf(P.w2[4],g1, fmaf(P.w2[5],g2, P.B2[1])));
    h2 = fmaf(P.w2[6],g0, fmaf(P.w2[7],g1, fmaf(P.w2[8],g2, P.B2[2])));
    if (USE_F){
        h0 = fmaf(P.t2[0], ftanh(h0), h0);
        h1 = fmaf(P.t2[1], ftanh(h1), h1);
        h2 = fmaf(P.t2[2], ftanh(h2), h2);
    }
    return fmaf(P.w3[0],h0, fmaf(P.w3[1],h1, fmaf(P.w3[2],h2, P.B3)));
}

template<bool USE_F>
__device__ __forceinline__ void elem(float xv, float nv, const Params& P, float& o, float& l){
    o = xv + nv - 0.5f;                       // quantize 'noise' mode
    float lo = eval_mlp<USE_F>(o - 0.5f, P);
    float hi = eval_mlp<USE_F>(o + 0.5f, P);
    float su = lo + hi;
    float s  = (su < 0.0f) ? 1.0f : ((su > 0.0f) ? -1.0f : 0.0f);   // -sign(lo+hi)
    float a  = fsig(s*hi);
    float b  = fsig(s*lo);
    l = fmaxf(fabsf(a - b), 1e-9f);           // LIKELIHOOD_BOUND
}

template<bool USE_F>
__device__ __forceinline__ void run_loop(const float4* __restrict__ x4, const float4* __restrict__ n4,
                                         float4* __restrict__ o4, float4* __restrict__ l4,
                                         int base, int tid, const Params& P){
    #pragma unroll
    for (int it = 0; it < ITERS; ++it){
        int i = base + it*THREADS + tid;
        float4 xv = x4[i];
        float4 nv = n4[i];
        float4 ov, lv;
        elem<USE_F>(xv.x, nv.x, P, ov.x, lv.x);
        elem<USE_F>(xv.y, nv.y, P, ov.y, lv.y);
        elem<USE_F>(xv.z, nv.z, P, ov.z, lv.z);
        elem<USE_F>(xv.w, nv.w, P, ov.w, lv.w);
        o4[i] = ov;
        l4[i] = lv;
    }
}

__global__ __launch_bounds__(THREADS) void eb_main(
    const float* __restrict__ x, const float* __restrict__ noise,
    const float* __restrict__ m0, const float* __restrict__ b0, const float* __restrict__ f0,
    const float* __restrict__ m1, const float* __restrict__ b1, const float* __restrict__ f1,
    const float* __restrict__ m2, const float* __restrict__ b2, const float* __restrict__ f2,
    const float* __restrict__ m3, const float* __restrict__ b3,
    float* __restrict__ out, float* __restrict__ lik)
{
    const int c   = blockIdx.y;
    const int tid = threadIdx.x;

    // slots: 0-2 w0 | 3-11 w1 | 12-20 w2 | 21-23 w3 | 24-26 t0 | 27-29 t1 |
    //        30-32 t2 | 33-35 B0 | 36-38 B1 | 39-41 B2 | 42 B3
    __shared__ float sp[43];
    if (tid < 43){
        float v;
        if      (tid <  3) v = fsoftplus(m0[c*3 + tid]);
        else if (tid < 12) v = fsoftplus(m1[c*9 + (tid-3)]);
        else if (tid < 21) v = fsoftplus(m2[c*9 + (tid-12)]);
        else if (tid < 24) v = fsoftplus(m3[c*3 + (tid-21)]);
        else if (tid < 27) v = tanhf(f0[c*3 + (tid-24)]);
        else if (tid < 30) v = tanhf(f1[c*3 + (tid-27)]);
        else if (tid < 33) v = tanhf(f2[c*3 + (tid-30)]);
        else if (tid < 36) v = b0[c*3 + (tid-33)];
        else if (tid < 39) v = b1[c*3 + (tid-36)];
        else if (tid < 42) v = b2[c*3 + (tid-39)];
        else               v = b3[c];
        sp[tid] = v;
    }
    __syncthreads();

    Params P;
    #pragma unroll
    for (int j=0;j<3;j++) P.w0[j]=sp[j];
    #pragma unroll
    for (int j=0;j<9;j++) P.w1[j]=sp[3+j];
    #pragma unroll
    for (int j=0;j<9;j++) P.w2[j]=sp[12+j];
    #pragma unroll
    for (int j=0;j<3;j++) P.w3[j]=sp[21+j];
    #pragma unroll
    for (int j=0;j<3;j++) P.t0[j]=sp[24+j];
    #pragma unroll
    for (int j=0;j<3;j++) P.t1[j]=sp[27+j];
    #pragma unroll
    for (int j=0;j<3;j++) P.t2[j]=sp[30+j];
    #pragma unroll
    for (int j=0;j<3;j++) P.B0[j]=sp[33+j];
    #pragma unroll
    for (int j=0;j<3;j++) P.B1[j]=sp[36+j];
    #pragma unroll
    for (int j=0;j<3;j++) P.B2[j]=sp[39+j];
    P.B3 = sp[42];

    // Runtime (block-uniform) check: setup_inputs has f==0 -> tanh(f)==0 ->
    // the tanh(z) correction terms vanish; skip 18 transcendentals/elem.
    bool use_f = false;
    #pragma unroll
    for (int j=0;j<3;j++)
        use_f = use_f || (P.t0[j]!=0.0f) || (P.t1[j]!=0.0f) || (P.t2[j]!=0.0f);

    const float4* x4 = (const float4*)x;
    const float4* n4 = (const float4*)noise;
    float4* o4 = (float4*)out;
    float4* l4 = (float4*)lik;
    const int base = c*(SPATIAL/4) + blockIdx.x*(ELEMS_PER_BLOCK/4);

    if (use_f) run_loop<true >(x4, n4, o4, l4, base, tid, P);
    else       run_loop<false>(x4, n4, o4, l4, base, tid, P);
}

// One block, 384 threads: one (channel, quantile) pair per thread, then reduce.
__global__ __launch_bounds__(384) void eb_quant(
    const float* __restrict__ m0, const float* __restrict__ b0, const float* __restrict__ f0,
    const float* __restrict__ m1, const float* __restrict__ b1, const float* __restrict__ f1,
    const float* __restrict__ m2, const float* __restrict__ b2, const float* __restrict__ f2,
    const float* __restrict__ m3, const float* __restrict__ b3,
    const float* __restrict__ q, float* __restrict__ loss)
{
    const int tid = threadIdx.x;
    const int c = tid / 3;
    const int j = tid - c*3;

    Params P;
    #pragma unroll
    for (int k=0;k<3;k++) P.w0[k]=fsoftplus(m0[c*3+k]);
    #pragma unroll
    for (int k=0;k<9;k++) P.w1[k]=fsoftplus(m1[c*9+k]);
    #pragma unroll
    for (int k=0;k<9;k++) P.w2[k]=fsoftplus(m2[c*9+k]);
    #pragma unroll
    for (int k=0;k<3;k++) P.w3[k]=fsoftplus(m3[c*3+k]);
    #pragma unroll
    for (int k=0;k<3;k++) P.t0[k]=tanhf(f0[c*3+k]);
    #pragma unroll
    for (int k=0;k<3;k++) P.t1[k]=tanhf(f1[c*3+k]);
    #pragma unroll
    for (int k=0;k<3;k++) P.t2[k]=tanhf(f2[c*3+k]);
    #pragma unroll
    for (int k=0;k<3;k++) P.B0[k]=b0[c*3+k];
    #pragma unroll
    for (int k=0;k<3;k++) P.B1[k]=b1[c*3+k];
    #pragma unroll
    for (int k=0;k<3;k++) P.B2[k]=b2[c*3+k];
    P.B3 = b3[c];

    float z      = q[c*3 + j];
    float logit  = eval_mlp<true>(z, P);
    float target = (j==0) ? -QT : ((j==1) ? 0.0f : QT);
    float diff   = fabsf(logit - target);

    // wave64 butterfly reduce, then cross-wave via LDS (384 = 6 waves)
    #pragma unroll
    for (int off = 32; off > 0; off >>= 1)
        diff += __shfl_down(diff, off, 64);

    __shared__ float red[6];
    if ((tid & 63) == 0) red[tid >> 6] = diff;
    __syncthreads();
    if (tid == 0){
        float s = 0.0f;
        #pragma unroll
        for (int i = 0; i < 6; i++) s += red[i];
        *loss = s;
    }
}

extern "C" void kernel_launch(void* const* d_in, const int* in_sizes, int n_in,
                              void* d_out, int out_size, void* d_ws, size_t ws_size,
                              hipStream_t stream) {
    // setup_inputs() dict order:
    // 0:x 1:noise 2:m0 3:b0 4:f0 5:m1 6:b1 7:f1 8:m2 9:b2 10:f2 11:m3 12:b3 13:quantiles
    const float* x  = (const float*)d_in[0];
    const float* nz = (const float*)d_in[1];
    const float* m0 = (const float*)d_in[2];
    const float* b0 = (const float*)d_in[3];
    const float* f0 = (const float*)d_in[4];
    const float* m1 = (const float*)d_in[5];
    const float* b1 = (const float*)d_in[6];
    const float* f1 = (const float*)d_in[7];
    const float* m2 = (const float*)d_in[8];
    const float* b2 = (const float*)d_in[9];
    const float* f2 = (const float*)d_in[10];
    const float* m3 = (const float*)d_in[11];
    const float* b3 = (const float*)d_in[12];
    const float* qq = (const float*)d_in[13];

    float* out  = (float*)d_out;
    float* lik  = out + (size_t)NCH*SPATIAL;
    float* loss = lik + (size_t)NCH*SPATIAL;

    dim3 grid(BLOCKS_X, NCH);
    eb_main<<<grid, THREADS, 0, stream>>>(x, nz, m0,b0,f0, m1,b1,f1, m2,b2,f2, m3,b3, out, lik);
    eb_quant<<<1, 384, 0, stream>>>(m0,b0,f0, m1,b1,f1, m2,b2,f2, m3,b3, qq, loss);
}

// Round 3
// 246.047 us; speedup vs baseline: 1.0174x; 1.0174x over previous
//
#include <hip/hip_runtime.h>
#include <math.h>

// Problem constants (SHAPE = (1, 128, 48, 48, 48), FILTERS = (1,3,3,3,1))
#define NCH      128
#define SPATIAL  110592            // 48*48*48
#define BLOCKS_X 27                // SPATIAL / ELEMS_PER_BLOCK
#define ELEMS_PER_BLOCK 4096
#define THREADS  256
#define ITERS    4                 // float4 iterations per thread: 4*256*4 = 4096 elems

#define QT 21.416413017506358f     // log(2/1e-9 - 1)

typedef float v4f __attribute__((ext_vector_type(4)));

__device__ __forceinline__ float frcp(float x){ return __builtin_amdgcn_rcpf(x); }
// tanh(x) = 1 - 2/(exp(2x)+1); saturates correctly at +-1 for large |x|
__device__ __forceinline__ float ftanh(float x){ return 1.0f - 2.0f*frcp(__expf(2.0f*x) + 1.0f); }
__device__ __forceinline__ float fsig(float x){ return frcp(1.0f + __expf(-x)); }
// softplus(x) = max(x,0) + log1p(exp(-|x|))  (robust for both signs)
__device__ __forceinline__ float fsoftplus(float x){ return fmaxf(x, 0.0f) + log1pf(__expf(-fabsf(x))); }

struct Params {
    float w0[3], w1[9], w2[9], w3[3];
    float t0[3], t1[3], t2[3];
    float B0[3], B1[3], B2[3], B3;
};

struct OL { float o, l; };

// z: scalar input; per-channel 4-layer CDF MLP (softplus weights pre-applied).
template<bool USE_F>
__device__ __forceinline__ float eval_mlp(float z, const Params& P){
    float h0 = fmaf(P.w0[0], z, P.B0[0]);
    float h1 = fmaf(P.w0[1], z, P.B0[1]);
    float h2 = fmaf(P.w0[2], z, P.B0[2]);
    if (USE_F){
        h0 = fmaf(P.t0[0], ftanh(h0), h0);
        h1 = fmaf(P.t0[1], ftanh(h1), h1);
        h2 = fmaf(P.t0[2], ftanh(h2), h2);
    }
    float g0 = fmaf(P.w1[0],h0, fmaf(P.w1[1],h1, fmaf(P.w1[2],h2, P.B1[0])));
    float g1 = fmaf(P.w1[3],h0, fmaf(P.w1[4],h1, fmaf(P.w1[5],h2, P.B1[1])));
    float g2 = fmaf(P.w1[6],h0, fmaf(P.w1[7],h1, fmaf(P.w1[8],h2, P.B1[2])));
    if (USE_F){
        g0 = fmaf(P.t1[0], ftanh(g0), g0);
        g1 = fmaf(P.t1[1], ftanh(g1), g1);
        g2 = fmaf(P.t1[2], ftanh(g2), g2);
    }
    h0 = fmaf(P.w2[0],g0, fmaf(P.w2[1],g1, fmaf(P.w2[2],g2, P.B2[0])));
    h1 = fmaf(P.w2[3],g0, fmaf(P.w2[4],g1, fmaf(P.w2[5],g2, P.B2[1])));
    h2 = fmaf(P.w2[6],g0, fmaf(P.w2[7],g1, fmaf(P.w2[8],g2, P.B2[2])));
    if (USE_F){
        h0 = fmaf(P.t2[0], ftanh(h0), h0);
        h1 = fmaf(P.t2[1], ftanh(h1), h1);
        h2 = fmaf(P.t2[2], ftanh(h2), h2);
    }
    return fmaf(P.w3[0],h0, fmaf(P.w3[1],h1, fmaf(P.w3[2],h2, P.B3)));
}

// ---- likelihood epilogue shared by both paths ----
__device__ __forceinline__ float lik_from_logits(float lo, float hi){
    float su = lo + hi;
    float s  = (su > 0.0f) ? -1.0f : ((su < 0.0f) ? 1.0f : 0.0f);   // -sign(lo+hi)
    float a  = fsig(s*hi);
    float b  = fsig(s*lo);
    return fmaxf(fabsf(a - b), 1e-9f);        // LIKELIHOOD_BOUND
}

// Fast path: MLP is exactly linear (all tanh(f)==0): logit(z) = A*z + B.
__device__ __forceinline__ OL elem_lin(float xv, float nv, float A, float Bl){
    OL r;
    r.o = xv + nv - 0.5f;
    float lo = fmaf(A, r.o, Bl);              // A*(o-0.5)+B, Bl = B - 0.5*A
    float hi = lo + A;                        // A*(o+0.5)+B
    r.l = lik_from_logits(lo, hi);
    return r;
}

// Slow path: general (nonzero factors)
__device__ __forceinline__ OL elem_full(float xv, float nv, const Params& P){
    OL r;
    r.o = xv + nv - 0.5f;
    float lo = eval_mlp<true>(r.o - 0.5f, P);
    float hi = eval_mlp<true>(r.o + 0.5f, P);
    r.l = lik_from_logits(lo, hi);
    return r;
}

__global__ __launch_bounds__(THREADS) void eb_main(
    const float* __restrict__ x, const float* __restrict__ noise,
    const float* __restrict__ m0, const float* __restrict__ b0, const float* __restrict__ f0,
    const float* __restrict__ m1, const float* __restrict__ b1, const float* __restrict__ f1,
    const float* __restrict__ m2, const float* __restrict__ b2, const float* __restrict__ f2,
    const float* __restrict__ m3, const float* __restrict__ b3,
    float* __restrict__ out, float* __restrict__ lik)
{
    const int c   = blockIdx.y;
    const int tid = threadIdx.x;

    // slots: 0-2 w0 | 3-11 w1 | 12-20 w2 | 21-23 w3 | 24-26 t0 | 27-29 t1 |
    //        30-32 t2 | 33-35 B0 | 36-38 B1 | 39-41 B2 | 42 B3
    __shared__ float sp[43];
    if (tid < 43){
        float v;
        if      (tid <  3) v = fsoftplus(m0[c*3 + tid]);
        else if (tid < 12) v = fsoftplus(m1[c*9 + (tid-3)]);
        else if (tid < 21) v = fsoftplus(m2[c*9 + (tid-12)]);
        else if (tid < 24) v = fsoftplus(m3[c*3 + (tid-21)]);
        else if (tid < 27) v = tanhf(f0[c*3 + (tid-24)]);
        else if (tid < 30) v = tanhf(f1[c*3 + (tid-27)]);
        else if (tid < 33) v = tanhf(f2[c*3 + (tid-30)]);
        else if (tid < 36) v = b0[c*3 + (tid-33)];
        else if (tid < 39) v = b1[c*3 + (tid-36)];
        else if (tid < 42) v = b2[c*3 + (tid-39)];
        else               v = b3[c];
        sp[tid] = v;
    }
    __syncthreads();

    Params P;
    #pragma unroll
    for (int j=0;j<3;j++) P.w0[j]=sp[j];
    #pragma unroll
    for (int j=0;j<9;j++) P.w1[j]=sp[3+j];
    #pragma unroll
    for (int j=0;j<9;j++) P.w2[j]=sp[12+j];
    #pragma unroll
    for (int j=0;j<3;j++) P.w3[j]=sp[21+j];
    #pragma unroll
    for (int j=0;j<3;j++) P.t0[j]=sp[24+j];
    #pragma unroll
    for (int j=0;j<3;j++) P.t1[j]=sp[27+j];
    #pragma unroll
    for (int j=0;j<3;j++) P.t2[j]=sp[30+j];
    #pragma unroll
    for (int j=0;j<3;j++) P.B0[j]=sp[33+j];
    #pragma unroll
    for (int j=0;j<3;j++) P.B1[j]=sp[36+j];
    #pragma unroll
    for (int j=0;j<3;j++) P.B2[j]=sp[39+j];
    P.B3 = sp[42];

    // Runtime (block-uniform) check: setup_inputs has f==0 -> tanh(f)==0 ->
    // MLP is exactly linear; collapse it to logit(z) = A*z + B.
    bool use_f = false;
    #pragma unroll
    for (int j=0;j<3;j++)
        use_f = use_f || (P.t0[j]!=0.0f) || (P.t1[j]!=0.0f) || (P.t2[j]!=0.0f);

    const v4f* __restrict__ x4 = (const v4f*)x;
    const v4f* __restrict__ n4 = (const v4f*)noise;
    v4f* __restrict__ o4 = (v4f*)out;
    v4f* __restrict__ l4 = (v4f*)lik;
    const int base = c*(SPATIAL/4) + blockIdx.x*(ELEMS_PER_BLOCK/4) + tid;

    if (!use_f){
        const float B  = eval_mlp<false>(0.0f, P);
        const float A  = eval_mlp<false>(1.0f, P) - B;
        const float Bl = B - 0.5f*A;

        // Batch ALL loads first -> 8 outstanding 16B loads/thread (max MLP),
        // then compute+store.
        v4f xv[ITERS], nv[ITERS];
        #pragma unroll
        for (int it = 0; it < ITERS; ++it){
            xv[it] = x4[base + it*THREADS];
            nv[it] = n4[base + it*THREADS];
        }
        #pragma unroll
        for (int it = 0; it < ITERS; ++it){
            v4f ov, lv;
            OL r0 = elem_lin(xv[it].x, nv[it].x, A, Bl);
            OL r1 = elem_lin(xv[it].y, nv[it].y, A, Bl);
            OL r2 = elem_lin(xv[it].z, nv[it].z, A, Bl);
            OL r3 = elem_lin(xv[it].w, nv[it].w, A, Bl);
            ov.x = r0.o; lv.x = r0.l;
            ov.y = r1.o; lv.y = r1.l;
            ov.z = r2.o; lv.z = r2.l;
            ov.w = r3.o; lv.w = r3.l;
            __builtin_nontemporal_store(ov, o4 + base + it*THREADS);
            __builtin_nontemporal_store(lv, l4 + base + it*THREADS);
        }
    } else {
        v4f xv[ITERS], nv[ITERS];
        #pragma unroll
        for (int it = 0; it < ITERS; ++it){
            xv[it] = x4[base + it*THREADS];
            nv[it] = n4[base + it*THREADS];
        }
        #pragma unroll
        for (int it = 0; it < ITERS; ++it){
            v4f ov, lv;
            OL r0 = elem_full(xv[it].x, nv[it].x, P);
            OL r1 = elem_full(xv[it].y, nv[it].y, P);
            OL r2 = elem_full(xv[it].z, nv[it].z, P);
            OL r3 = elem_full(xv[it].w, nv[it].w, P);
            ov.x = r0.o; lv.x = r0.l;
            ov.y = r1.o; lv.y = r1.l;
            ov.z = r2.o; lv.z = r2.l;
            ov.w = r3.o; lv.w = r3.l;
            __builtin_nontemporal_store(ov, o4 + base + it*THREADS);
            __builtin_nontemporal_store(lv, l4 + base + it*THREADS);
        }
    }
}

// One block, 384 threads: one (channel, quantile) pair per thread, then reduce.
__global__ __launch_bounds__(384) void eb_quant(
    const float* __restrict__ m0, const float* __restrict__ b0, const float* __restrict__ f0,
    const float* __restrict__ m1, const float* __restrict__ b1, const float* __restrict__ f1,
    const float* __restrict__ m2, const float* __restrict__ b2, const float* __restrict__ f2,
    const float* __restrict__ m3, const float* __restrict__ b3,
    const float* __restrict__ q, float* __restrict__ loss)
{
    const int tid = threadIdx.x;
    const int c = tid / 3;
    const int j = tid - c*3;

    Params P;
    #pragma unroll
    for (int k=0;k<3;k++) P.w0[k]=fsoftplus(m0[c*3+k]);
    #pragma unroll
    for (int k=0;k<9;k++) P.w1[k]=fsoftplus(m1[c*9+k]);
    #pragma unroll
    for (int k=0;k<9;k++) P.w2[k]=fsoftplus(m2[c*9+k]);
    #pragma unroll
    for (int k=0;k<3;k++) P.w3[k]=fsoftplus(m3[c*3+k]);
    #pragma unroll
    for (int k=0;k<3;k++) P.t0[k]=tanhf(f0[c*3+k]);
    #pragma unroll
    for (int k=0;k<3;k++) P.t1[k]=tanhf(f1[c*3+k]);
    #pragma unroll
    for (int k=0;k<3;k++) P.t2[k]=tanhf(f2[c*3+k]);
    #pragma unroll
    for (int k=0;k<3;k++) P.B0[k]=b0[c*3+k];
    #pragma unroll
    for (int k=0;k<3;k++) P.B1[k]=b1[c*3+k];
    #pragma unroll
    for (int k=0;k<3;k++) P.B2[k]=b2[c*3+k];
    P.B3 = b3[c];

    float z      = q[c*3 + j];
    float logit  = eval_mlp<true>(z, P);
    float target = (j==0) ? -QT : ((j==1) ? 0.0f : QT);
    float diff   = fabsf(logit - target);

    // wave64 butterfly reduce, then cross-wave via LDS (384 = 6 waves)
    #pragma unroll
    for (int off = 32; off > 0; off >>= 1)
        diff += __shfl_down(diff, off, 64);

    __shared__ float red[6];
    if ((tid & 63) == 0) red[tid >> 6] = diff;
    __syncthreads();
    if (tid == 0){
        float s = 0.0f;
        #pragma unroll
        for (int i = 0; i < 6; i++) s += red[i];
        *loss = s;
    }
}

extern "C" void kernel_launch(void* const* d_in, const int* in_sizes, int n_in,
                              void* d_out, int out_size, void* d_ws, size_t ws_size,
                              hipStream_t stream) {
    // setup_inputs() dict order:
    // 0:x 1:noise 2:m0 3:b0 4:f0 5:m1 6:b1 7:f1 8:m2 9:b2 10:f2 11:m3 12:b3 13:quantiles
    const float* x  = (const float*)d_in[0];
    const float* nz = (const float*)d_in[1];
    const float* m0 = (const float*)d_in[2];
    const float* b0 = (const float*)d_in[3];
    const float* f0 = (const float*)d_in[4];
    const float* m1 = (const float*)d_in[5];
    const float* b1 = (const float*)d_in[6];
    const float* f1 = (const float*)d_in[7];
    const float* m2 = (const float*)d_in[8];
    const float* b2 = (const float*)d_in[9];
    const float* f2 = (const float*)d_in[10];
    const float* m3 = (const float*)d_in[11];
    const float* b3 = (const float*)d_in[12];
    const float* qq = (const float*)d_in[13];

    float* out  = (float*)d_out;
    float* lik  = out + (size_t)NCH*SPATIAL;
    float* loss = lik + (size_t)NCH*SPATIAL;

    dim3 grid(BLOCKS_X, NCH);
    eb_main<<<grid, THREADS, 0, stream>>>(x, nz, m0,b0,f0, m1,b1,f1, m2,b2,f2, m3,b3, out, lik);
    eb_quant<<<1, 384, 0, stream>>>(m0,b0,f0, m1,b1,f1, m2,b2,f2, m3,b3, qq, loss);
}

// Round 4
// 231.397 us; speedup vs baseline: 1.0818x; 1.0633x over previous
//
#include <hip/hip_runtime.h>
#include <math.h>

// Problem constants (SHAPE = (1, 128, 48, 48, 48), FILTERS = (1,3,3,3,1))
#define NCH      128
#define SPATIAL  110592            // 48*48*48
#define NV4      3538944           // NCH*SPATIAL/4 total float4 groups
#define CV4      27648             // SPATIAL/4 float4 groups per channel
#define THREADS  256
#define GRID     2048              // 8 blocks/CU * 256 CUs -> fully resident, persistent

#define QT 21.416413017506358f     // log(2/1e-9 - 1)

typedef float v4f __attribute__((ext_vector_type(4)));

__device__ __forceinline__ float frcp(float x){ return __builtin_amdgcn_rcpf(x); }
__device__ __forceinline__ float ftanh(float x){ return 1.0f - 2.0f*frcp(__expf(2.0f*x) + 1.0f); }
__device__ __forceinline__ float fsig(float x){ return frcp(1.0f + __expf(-x)); }
__device__ __forceinline__ float fsoftplus(float x){ return fmaxf(x, 0.0f) + log1pf(__expf(-fabsf(x))); }

struct Params {
    float w0[3], w1[9], w2[9], w3[3];
    float t0[3], t1[3], t2[3];
    float B0[3], B1[3], B2[3], B3;
};

__device__ __forceinline__ Params load_params(int c,
    const float* __restrict__ m0, const float* __restrict__ b0, const float* __restrict__ f0,
    const float* __restrict__ m1, const float* __restrict__ b1, const float* __restrict__ f1,
    const float* __restrict__ m2, const float* __restrict__ b2, const float* __restrict__ f2,
    const float* __restrict__ m3, const float* __restrict__ b3)
{
    Params P;
    #pragma unroll
    for (int k=0;k<3;k++) P.w0[k]=fsoftplus(m0[c*3+k]);
    #pragma unroll
    for (int k=0;k<9;k++) P.w1[k]=fsoftplus(m1[c*9+k]);
    #pragma unroll
    for (int k=0;k<9;k++) P.w2[k]=fsoftplus(m2[c*9+k]);
    #pragma unroll
    for (int k=0;k<3;k++) P.w3[k]=fsoftplus(m3[c*3+k]);
    #pragma unroll
    for (int k=0;k<3;k++) P.t0[k]=ftanh(f0[c*3+k]);
    #pragma unroll
    for (int k=0;k<3;k++) P.t1[k]=ftanh(f1[c*3+k]);
    #pragma unroll
    for (int k=0;k<3;k++) P.t2[k]=ftanh(f2[c*3+k]);
    #pragma unroll
    for (int k=0;k<3;k++) P.B0[k]=b0[c*3+k];
    #pragma unroll
    for (int k=0;k<3;k++) P.B1[k]=b1[c*3+k];
    #pragma unroll
    for (int k=0;k<3;k++) P.B2[k]=b2[c*3+k];
    P.B3 = b3[c];
    return P;
}

template<bool USE_F>
__device__ __forceinline__ float eval_mlp(float z, const Params& P){
    float h0 = fmaf(P.w0[0], z, P.B0[0]);
    float h1 = fmaf(P.w0[1], z, P.B0[1]);
    float h2 = fmaf(P.w0[2], z, P.B0[2]);
    if (USE_F){
        h0 = fmaf(P.t0[0], ftanh(h0), h0);
        h1 = fmaf(P.t0[1], ftanh(h1), h1);
        h2 = fmaf(P.t0[2], ftanh(h2), h2);
    }
    float g0 = fmaf(P.w1[0],h0, fmaf(P.w1[1],h1, fmaf(P.w1[2],h2, P.B1[0])));
    float g1 = fmaf(P.w1[3],h0, fmaf(P.w1[4],h1, fmaf(P.w1[5],h2, P.B1[1])));
    float g2 = fmaf(P.w1[6],h0, fmaf(P.w1[7],h1, fmaf(P.w1[8],h2, P.B1[2])));
    if (USE_F){
        g0 = fmaf(P.t1[0], ftanh(g0), g0);
        g1 = fmaf(P.t1[1], ftanh(g1), g1);
        g2 = fmaf(P.t1[2], ftanh(g2), g2);
    }
    h0 = fmaf(P.w2[0],g0, fmaf(P.w2[1],g1, fmaf(P.w2[2],g2, P.B2[0])));
    h1 = fmaf(P.w2[3],g0, fmaf(P.w2[4],g1, fmaf(P.w2[5],g2, P.B2[1])));
    h2 = fmaf(P.w2[6],g0, fmaf(P.w2[7],g1, fmaf(P.w2[8],g2, P.B2[2])));
    if (USE_F){
        h0 = fmaf(P.t2[0], ftanh(h0), h0);
        h1 = fmaf(P.t2[1], ftanh(h1), h1);
        h2 = fmaf(P.t2[2], ftanh(h2), h2);
    }
    return fmaf(P.w3[0],h0, fmaf(P.w3[1],h1, fmaf(P.w3[2],h2, P.B3)));
}

__device__ __forceinline__ float lik_from_logits(float lo, float hi){
    float su = lo + hi;
    float s  = (su > 0.0f) ? -1.0f : ((su < 0.0f) ? 1.0f : 0.0f);   // -sign(lo+hi)
    float a  = fsig(s*hi);
    float b  = fsig(s*lo);
    return fmaxf(fabsf(a - b), 1e-9f);        // LIKELIHOOD_BOUND
}

// ---------------------------------------------------------------------------
// Prep kernel (1 block, 384 threads): per-(channel,quantile) quantiles_loss,
// per-channel linear collapse (A, Bl) -> ws, and the use_f flag -> ws.
// ---------------------------------------------------------------------------
__global__ __launch_bounds__(384) void eb_prep(
    const float* __restrict__ m0, const float* __restrict__ b0, const float* __restrict__ f0,
    const float* __restrict__ m1, const float* __restrict__ b1, const float* __restrict__ f1,
    const float* __restrict__ m2, const float* __restrict__ b2, const float* __restrict__ f2,
    const float* __restrict__ m3, const float* __restrict__ b3,
    const float* __restrict__ q, float* __restrict__ loss,
    float2* __restrict__ ab, int* __restrict__ flag)
{
    const int tid = threadIdx.x;
    const int c = tid / 3;
    const int j = tid - c*3;

    Params P = load_params(c, m0,b0,f0, m1,b1,f1, m2,b2,f2, m3,b3);

    bool anyf = false;
    #pragma unroll
    for (int k=0;k<3;k++)
        anyf = anyf || (P.t0[k]!=0.0f) || (P.t1[k]!=0.0f) || (P.t2[k]!=0.0f);

    __shared__ int sf;
    if (tid == 0) sf = 0;
    __syncthreads();
    if (anyf) sf = 1;                        // benign race: all writers store 1

    float z      = q[c*3 + j];
    float logit  = eval_mlp<true>(z, P);
    float target = (j==0) ? -QT : ((j==1) ? 0.0f : QT);
    float diff   = fabsf(logit - target);

    #pragma unroll
    for (int off = 32; off > 0; off >>= 1)
        diff += __shfl_down(diff, off, 64);

    __shared__ float red[6];
    if ((tid & 63) == 0) red[tid >> 6] = diff;
    __syncthreads();                         // publishes red[] and sf
    if (tid == 0){
        float s = 0.0f;
        #pragma unroll
        for (int i = 0; i < 6; i++) s += red[i];
        *loss = s;
        *flag = sf;
    }

    if (j == 0){                             // one thread per channel
        float B = eval_mlp<false>(0.0f, P);
        float A = eval_mlp<false>(1.0f, P) - B;
        ab[c] = make_float2(A, B - 0.5f*A);  // Bl = B - A/2
    }
}

// ---------------------------------------------------------------------------
// Main kernel: persistent grid-stride, double-buffered loads, NT stores.
// ---------------------------------------------------------------------------
__global__ __launch_bounds__(THREADS) void eb_main(
    const float* __restrict__ x, const float* __restrict__ noise,
    const float* __restrict__ m0, const float* __restrict__ b0, const float* __restrict__ f0,
    const float* __restrict__ m1, const float* __restrict__ b1, const float* __restrict__ f1,
    const float* __restrict__ m2, const float* __restrict__ b2, const float* __restrict__ f2,
    const float* __restrict__ m3, const float* __restrict__ b3,
    const float2* __restrict__ ab, const int* __restrict__ flag,
    float* __restrict__ out, float* __restrict__ lik)
{
    __shared__ float sA[NCH], sBl[NCH];
    __shared__ int sflag;
    const int tid = threadIdx.x;
    if (tid < NCH){ float2 v = ab[tid]; sA[tid] = v.x; sBl[tid] = v.y; }
    if (tid == 0) sflag = *flag;
    __syncthreads();
    const bool use_f = (sflag != 0);

    const v4f* __restrict__ x4 = (const v4f*)x;
    const v4f* __restrict__ n4 = (const v4f*)noise;
    v4f* __restrict__ o4 = (v4f*)out;
    v4f* __restrict__ l4 = (v4f*)lik;

    int i = blockIdx.x*THREADS + tid;        // < GRID*THREADS = 524288 < NV4
    const int stride = GRID*THREADS;

    if (!use_f){
        // software pipeline: prefetch tile k+1 while computing tile k
        v4f xa = x4[i], na = n4[i];
        while (true){
            const int inext = i + stride;
            const bool vnext = inext < NV4;
            v4f xb, nb;
            if (vnext){ xb = x4[inext]; nb = n4[inext]; }

            const int c = i / CV4;           // channel (magic-mul div)
            const float A  = sA[c];
            const float Bl = sBl[c];

            v4f ov, lv;
            #pragma unroll
            for (int e = 0; e < 4; ++e){
                float o  = xa[e] + na[e] - 0.5f;
                float lo = fmaf(A, o, Bl);   // logit(o-0.5)
                float hi = lo + A;           // logit(o+0.5)
                ov[e] = o;
                lv[e] = lik_from_logits(lo, hi);
            }
            __builtin_nontemporal_store(ov, o4 + i);
            __builtin_nontemporal_store(lv, l4 + i);

            if (!vnext) break;
            i = inext; xa = xb; na = nb;
        }
    } else {
        // General path (nonzero factors): correct, params re-read via L1/L2.
        for (; i < NV4; i += stride){
            const int c = i / CV4;
            Params P = load_params(c, m0,b0,f0, m1,b1,f1, m2,b2,f2, m3,b3);
            v4f xv = x4[i], nv = n4[i];
            v4f ov, lv;
            #pragma unroll
            for (int e = 0; e < 4; ++e){
                float o  = xv[e] + nv[e] - 0.5f;
                float lo = eval_mlp<true>(o - 0.5f, P);
                float hi = eval_mlp<true>(o + 0.5f, P);
                ov[e] = o;
                lv[e] = lik_from_logits(lo, hi);
            }
            __builtin_nontemporal_store(ov, o4 + i);
            __builtin_nontemporal_store(lv, l4 + i);
        }
    }
}

extern "C" void kernel_launch(void* const* d_in, const int* in_sizes, int n_in,
                              void* d_out, int out_size, void* d_ws, size_t ws_size,
                              hipStream_t stream) {
    // setup_inputs() dict order:
    // 0:x 1:noise 2:m0 3:b0 4:f0 5:m1 6:b1 7:f1 8:m2 9:b2 10:f2 11:m3 12:b3 13:quantiles
    const float* x  = (const float*)d_in[0];
    const float* nz = (const float*)d_in[1];
    const float* m0 = (const float*)d_in[2];
    const float* b0 = (const float*)d_in[3];
    const float* f0 = (const float*)d_in[4];
    const float* m1 = (const float*)d_in[5];
    const float* b1 = (const float*)d_in[6];
    const float* f1 = (const float*)d_in[7];
    const float* m2 = (const float*)d_in[8];
    const float* b2 = (const float*)d_in[9];
    const float* f2 = (const float*)d_in[10];
    const float* m3 = (const float*)d_in[11];
    const float* b3 = (const float*)d_in[12];
    const float* qq = (const float*)d_in[13];

    float* out  = (float*)d_out;
    float* lik  = out + (size_t)NCH*SPATIAL;
    float* loss = lik + (size_t)NCH*SPATIAL;

    float2* ab  = (float2*)d_ws;             // 128 * 8 B
    int*   flag = (int*)((char*)d_ws + NCH*sizeof(float2));

    eb_prep<<<1, 384, 0, stream>>>(m0,b0,f0, m1,b1,f1, m2,b2,f2, m3,b3, qq, loss, ab, flag);
    eb_main<<<GRID, THREADS, 0, stream>>>(x, nz, m0,b0,f0, m1,b1,f1, m2,b2,f2, m3,b3,
                                          ab, flag, out, lik);
}